// Round 8
// baseline (39.126 us; speedup 1.0000x reference)
//
#include <hip/hip_runtime.h>
#include <hip/hip_bf16.h>

#define D_MODEL 4096
#define NN      4403      // selected neurons
#define NB      64        // batch
#define BN      128       // neurons per block (4 waves x 32)
#define KCH     256       // K per block
#define KSPLIT  (D_MODEL / KCH)           // 16
#define NT      ((NN + BN - 1) / BN)      // 35 neuron tiles
#define LDX     264       // shorts per X row in LDS (132 dw ≡ 4 mod 32 -> ≤2-way on frag reads)
#define OUT_ELEMS (NB * NN)               // 281792
// bf16 partials, tile-packed [KSPLIT][NT][128 cols][64 rows]
#define P_TILE_ELEMS (BN * NB)                            // 8192
#define WS_NEEDED ((size_t)KSPLIT * NT * P_TILE_ELEMS * 2)   // ~9.2 MB

using f32x4  = __attribute__((ext_vector_type(4))) float;
using bf16x8 = __attribute__((ext_vector_type(8))) short;
using u16x8  = __attribute__((ext_vector_type(8))) unsigned short;
using u16x4  = __attribute__((ext_vector_type(4))) unsigned short;

__device__ __forceinline__ unsigned short f2bf(float f) {
    __hip_bfloat16 h = __float2bfloat16(f);     // RNE
    return __builtin_bit_cast(unsigned short, h);
}

__device__ __forceinline__ u16x8 pack8(f32x4 a, f32x4 b) {
    u16x8 v;
    v[0] = f2bf(a[0]); v[1] = f2bf(a[1]); v[2] = f2bf(a[2]); v[3] = f2bf(a[3]);
    v[4] = f2bf(b[0]); v[5] = f2bf(b[1]); v[6] = f2bf(b[2]); v[7] = f2bf(b[3]);
    return v;
}

// 4 waves; wave owns 32 neurons (2 B-frags). X bf16 panel in 33 KB LDS.
// 3 blocks/CU resident. Partials written bf16, tile-packed col-major.
__global__ __launch_bounds__(256, 3)
void gather_gemm(const float* __restrict__ X,
                 const float* __restrict__ W,
                 const int*   __restrict__ idx,
                 unsigned short* __restrict__ P)
{
    __shared__ __align__(16) unsigned short Xs[64 * LDX];   // 33 KB

    const int tid   = threadIdx.x;
    const int wave  = tid >> 6;
    const int lane  = tid & 63;
    const int fr    = lane & 15;       // neuron within sub-tile
    const int g     = lane >> 4;       // k-group
    const int fk    = g * 8;

    const int n0    = blockIdx.x * BN;
    const int kbase = blockIdx.y * KCH;

    // ---- W pointers: 2 gathered rows per lane ----
    const int na = n0 + wave * 32 + fr;
    const int nb = na + 16;
    const int ra = idx[(na < NN) ? na : (NN - 1)];
    const int rb = idx[(nb < NN) ? nb : (NN - 1)];
    const float* wpa = W + (size_t)ra * D_MODEL + kbase + fk;
    const float* wpb = W + (size_t)rb * D_MODEL + kbase + fk;

    // ---- group 0 W loads (kfrags 0..3), 64 VGPR in flight ----
    f32x4 raw[4][2][2];                // [kfrag][n][half]
#pragma unroll
    for (int kf = 0; kf < 4; ++kf) {
        raw[kf][0][0] = *(const f32x4*)(wpa + kf * 32);
        raw[kf][0][1] = *(const f32x4*)(wpa + kf * 32 + 4);
        raw[kf][1][0] = *(const f32x4*)(wpb + kf * 32);
        raw[kf][1][1] = *(const f32x4*)(wpb + kf * 32 + 4);
    }

    // ---- X staging: 64 rows x 256 f32 -> bf16, contiguous 1 KB row reads ----
    {
        const int row8 = tid >> 5;             // 0..7
        const int colf = (tid & 31) * 8;       // float offset within row
#pragma unroll
        for (int p = 0; p < 8; ++p) {
            const int row = p * 8 + row8;
            const float* xp = X + (size_t)row * D_MODEL + kbase + colf;
            f32x4 a = *(const f32x4*)(xp + 0);
            f32x4 b = *(const f32x4*)(xp + 4);
            *(u16x8*)&Xs[row * LDX + colf] = pack8(a, b);
        }
    }
    __syncthreads();

    f32x4 acc[4][2];
#pragma unroll
    for (int m = 0; m < 4; ++m)
#pragma unroll
        for (int j = 0; j < 2; ++j) acc[m][j] = (f32x4){0.f, 0.f, 0.f, 0.f};

    // convert group 0, then issue group 1 loads (reuse raw), MFMA overlaps
    bf16x8 bw[4][2];
#pragma unroll
    for (int kf = 0; kf < 4; ++kf) {
        bw[kf][0] = __builtin_bit_cast(bf16x8, pack8(raw[kf][0][0], raw[kf][0][1]));
        bw[kf][1] = __builtin_bit_cast(bf16x8, pack8(raw[kf][1][0], raw[kf][1][1]));
    }
#pragma unroll
    for (int kf = 0; kf < 4; ++kf) {
        raw[kf][0][0] = *(const f32x4*)(wpa + 128 + kf * 32);
        raw[kf][0][1] = *(const f32x4*)(wpa + 128 + kf * 32 + 4);
        raw[kf][1][0] = *(const f32x4*)(wpb + 128 + kf * 32);
        raw[kf][1][1] = *(const f32x4*)(wpb + 128 + kf * 32 + 4);
    }
#pragma unroll
    for (int kf = 0; kf < 4; ++kf) {
#pragma unroll
        for (int m = 0; m < 4; ++m) {
            bf16x8 af = *(const bf16x8*)&Xs[(m * 16 + fr) * LDX + kf * 32 + fk];
            acc[m][0] = __builtin_amdgcn_mfma_f32_16x16x32_bf16(af, bw[kf][0], acc[m][0], 0, 0, 0);
            acc[m][1] = __builtin_amdgcn_mfma_f32_16x16x32_bf16(af, bw[kf][1], acc[m][1], 0, 0, 0);
        }
    }
#pragma unroll
    for (int kf = 0; kf < 4; ++kf) {
        bw[kf][0] = __builtin_bit_cast(bf16x8, pack8(raw[kf][0][0], raw[kf][0][1]));
        bw[kf][1] = __builtin_bit_cast(bf16x8, pack8(raw[kf][1][0], raw[kf][1][1]));
    }
#pragma unroll
    for (int kf = 0; kf < 4; ++kf) {
#pragma unroll
        for (int m = 0; m < 4; ++m) {
            bf16x8 af = *(const bf16x8*)&Xs[(m * 16 + fr) * LDX + (4 + kf) * 32 + fk];
            acc[m][0] = __builtin_amdgcn_mfma_f32_16x16x32_bf16(af, bw[kf][0], acc[m][0], 0, 0, 0);
            acc[m][1] = __builtin_amdgcn_mfma_f32_16x16x32_bf16(af, bw[kf][1], acc[m][1], 0, 0, 0);
        }
    }

    // ---- epilogue: bf16 partials, tile-packed [s][tile][col 0..127][row 0..63]
    // lane writes 4 consecutive rows (8 B) per (m,j): fully covered cache lines per wave
    unsigned short* tbase = P + (((size_t)blockIdx.y * NT + blockIdx.x) * BN) * NB;
#pragma unroll
    for (int j = 0; j < 2; ++j) {
        const int c = wave * 32 + 16 * j + fr;           // tile-local col
#pragma unroll
        for (int m = 0; m < 4; ++m) {
            const int brow = m * 16 + g * 4;
            u16x4 pk;
#pragma unroll
            for (int r = 0; r < 4; ++r) pk[r] = f2bf(acc[m][j][r]);
            *(u16x4*)&tbase[(size_t)c * NB + brow] = pk;
        }
    }
}

// sum 16 bf16 slabs -> fp32 out. thread = (tile, row4, col): reads 8 B
// contiguous per slab, writes 4 floats (row-coalesced across the wave).
__global__ __launch_bounds__(256)
void reduce_splitk(const unsigned short* __restrict__ P, float* __restrict__ out) {
    const int id   = blockIdx.x * 256 + threadIdx.x;     // 0 .. 35*16*128-1
    const int col  = id & 127;
    const int row4 = (id >> 7) & 15;
    const int tile = id >> 11;
    if (tile >= NT) return;

    const int ncol = tile * BN + col;
    float s0 = 0.f, s1 = 0.f, s2 = 0.f, s3 = 0.f;
#pragma unroll
    for (int s = 0; s < KSPLIT; ++s) {
        const unsigned short* p = P + (((size_t)s * NT + tile) * BN + col) * NB + row4 * 4;
        u16x4 v = *(const u16x4*)p;
        s0 += __uint_as_float((unsigned)v[0] << 16);
        s1 += __uint_as_float((unsigned)v[1] << 16);
        s2 += __uint_as_float((unsigned)v[2] << 16);
        s3 += __uint_as_float((unsigned)v[3] << 16);
    }
    if (ncol < NN) {
        const int row = row4 * 4;
        out[(size_t)(row + 0) * NN + ncol] = s0;
        out[(size_t)(row + 1) * NN + ncol] = s1;
        out[(size_t)(row + 2) * NN + ncol] = s2;
        out[(size_t)(row + 3) * NN + ncol] = s3;
    }
}

// ---------------- Fallback (ws too small): one-pass atomic version ----------------
__global__ __launch_bounds__(256, 3)
void gather_gemm_atomic(const float* __restrict__ X,
                        const float* __restrict__ W,
                        const int*   __restrict__ idx,
                        float* __restrict__ out)
{
    __shared__ __align__(16) unsigned short Xs[64 * LDX];
    const int tid  = threadIdx.x;
    const int wave = tid >> 6;
    const int lane = tid & 63;
    const int fr = lane & 15, g = lane >> 4, fk = g * 8;
    const int n0 = blockIdx.x * 64;
    const int kbase = blockIdx.y * KCH;
    const int n = n0 + wave * 16 + fr;
    const int wrow = idx[(n < NN) ? n : (NN - 1)];
    const float* wp = W + (size_t)wrow * D_MODEL + kbase + fk;
    f32x4 wa[8][2];
#pragma unroll
    for (int s = 0; s < 8; ++s) {
        wa[s][0] = *(const f32x4*)(wp + s * 32);
        wa[s][1] = *(const f32x4*)(wp + s * 32 + 4);
    }
    {
        const int row8 = tid >> 5, colf = (tid & 31) * 8;
#pragma unroll
        for (int p = 0; p < 8; ++p) {
            const int row = p * 8 + row8;
            const float* xp = X + (size_t)row * D_MODEL + kbase + colf;
            f32x4 a = *(const f32x4*)(xp + 0);
            f32x4 b = *(const f32x4*)(xp + 4);
            *(u16x8*)&Xs[row * LDX + colf] = pack8(a, b);
        }
    }
    __syncthreads();
    f32x4 acc[4];
#pragma unroll
    for (int m = 0; m < 4; ++m) acc[m] = (f32x4){0.f, 0.f, 0.f, 0.f};
#pragma unroll
    for (int s = 0; s < 8; ++s) {
        bf16x8 wf = __builtin_bit_cast(bf16x8, pack8(wa[s][0], wa[s][1]));
#pragma unroll
        for (int m = 0; m < 4; ++m) {
            bf16x8 af = *(const bf16x8*)&Xs[(m * 16 + fr) * LDX + s * 32 + fk];
            acc[m] = __builtin_amdgcn_mfma_f32_16x16x32_bf16(af, wf, acc[m], 0, 0, 0);
        }
    }
    const int ncol = n0 + wave * 16 + fr;
    if (ncol < NN) {
#pragma unroll
        for (int m = 0; m < 4; ++m) {
            int brow = m * 16 + g * 4;
#pragma unroll
            for (int r = 0; r < 4; ++r)
                atomicAdd(&out[(size_t)(brow + r) * NN + ncol], acc[m][r]);
        }
    }
}

extern "C" void kernel_launch(void* const* d_in, const int* in_sizes, int n_in,
                              void* d_out, int out_size, void* d_ws, size_t ws_size,
                              hipStream_t stream) {
    const float* X   = (const float*)d_in[0];   // [64,1,4096] f32
    const float* W   = (const float*)d_in[1];   // [11008,4096] f32
    const int*   idx = (const int*)d_in[2];     // [4403] i32
    float* out = (float*)d_out;                 // [64,1,4403] f32

    if (ws_size >= WS_NEEDED) {
        unsigned short* P = (unsigned short*)d_ws;
        dim3 grid(NT, KSPLIT, 1);   // 35 x 16 = 560 blocks, 3/CU resident
        gather_gemm<<<grid, 256, 0, stream>>>(X, W, idx, P);
        int nthreads = NT * 16 * 128;           // 71680
        reduce_splitk<<<(nthreads + 255) / 256, 256, 0, stream>>>(P, out);
    } else {
        hipMemsetAsync(d_out, 0, (size_t)out_size * sizeof(float), stream);
        dim3 grid((NN + 63) / 64, KSPLIT, 1);
        gather_gemm_atomic<<<grid, 256, 0, stream>>>(X, W, idx, out);
    }
}

// Round 9
// 29.037 us; speedup vs baseline: 1.3475x; 1.3475x over previous
//
#include <hip/hip_runtime.h>
#include <hip/hip_bf16.h>

#define D_MODEL 4096
#define NN      4403      // selected neurons
#define NNP     4480      // padded cols = 35*128 (every P slot written)
#define NB      64        // batch
#define BN      128       // neurons per block (4 waves x 32)
#define KCH     256       // K per block
#define KSPLIT  (D_MODEL / KCH)           // 16
#define NT      ((NN + BN - 1) / BN)      // 35 neuron tiles
#define LDX     264       // shorts per X row in LDS
#define WS_NEEDED ((size_t)KSPLIT * NB * NNP * 2)    // ~11.5 MB bf16 partials

using f32x4  = __attribute__((ext_vector_type(4))) float;
using bf16x8 = __attribute__((ext_vector_type(8))) short;
using u16x8  = __attribute__((ext_vector_type(8))) unsigned short;

__device__ __forceinline__ unsigned short f2bf(float f) {
    __hip_bfloat16 h = __float2bfloat16(f);     // RNE
    return __builtin_bit_cast(unsigned short, h);
}

__device__ __forceinline__ u16x8 pack8(f32x4 a, f32x4 b) {
    u16x8 v;
    v[0] = f2bf(a[0]); v[1] = f2bf(a[1]); v[2] = f2bf(a[2]); v[3] = f2bf(a[3]);
    v[4] = f2bf(b[0]); v[5] = f2bf(b[1]); v[6] = f2bf(b[2]); v[7] = f2bf(b[3]);
    return v;
}

// BN=128: wave owns 32 neurons x 64 batch. W fully reg-prefetched (16 dwordx4
// in flight), X bf16 panel in 33 KB LDS, single barrier. waves=2 -> no spill.
__global__ __launch_bounds__(256, 2)
void gather_gemm(const float* __restrict__ X,
                 const float* __restrict__ W,
                 const int*   __restrict__ idx,
                 unsigned short* __restrict__ P)
{
    __shared__ __align__(16) unsigned short Xs[64 * LDX];   // 33 KB

    const int tid   = threadIdx.x;
    const int wave  = tid >> 6;
    const int lane  = tid & 63;
    const int fr    = lane & 15;       // neuron within 16-sub-tile
    const int g     = lane >> 4;       // k-group
    const int fk    = g * 8;

    const int n0    = blockIdx.x * BN;
    const int kbase = blockIdx.y * KCH;

    // ---- W: 2 gathered rows per lane, FULL-depth prefetch (128 VGPR in flight) ----
    const int na = n0 + wave * 32 + fr;
    const int nb = na + 16;
    const int ra = idx[(na < NN) ? na : (NN - 1)];
    const int rb = idx[(nb < NN) ? nb : (NN - 1)];
    const float* wpa = W + (size_t)ra * D_MODEL + kbase + fk;
    const float* wpb = W + (size_t)rb * D_MODEL + kbase + fk;

    f32x4 raw[8][2][2];                // [kfrag][n-half][quad]
#pragma unroll
    for (int kf = 0; kf < 8; ++kf) {
        raw[kf][0][0] = *(const f32x4*)(wpa + kf * 32);
        raw[kf][0][1] = *(const f32x4*)(wpa + kf * 32 + 4);
        raw[kf][1][0] = *(const f32x4*)(wpb + kf * 32);
        raw[kf][1][1] = *(const f32x4*)(wpb + kf * 32 + 4);
    }

    // ---- X staging: 64 rows x 256 f32 -> bf16, contiguous 1 KB row reads ----
    {
        const int row8 = tid >> 5;             // 0..7
        const int colf = (tid & 31) * 8;       // float offset within row
#pragma unroll
        for (int p = 0; p < 8; ++p) {
            const int row = p * 8 + row8;
            const float* xp = X + (size_t)row * D_MODEL + kbase + colf;
            f32x4 a = *(const f32x4*)(xp + 0);
            f32x4 b = *(const f32x4*)(xp + 4);
            *(u16x8*)&Xs[row * LDX + colf] = pack8(a, b);
        }
    }
    __syncthreads();   // single drain: every W + X load retired here

    f32x4 acc[4][2];
#pragma unroll
    for (int m = 0; m < 4; ++m)
#pragma unroll
        for (int j = 0; j < 2; ++j) acc[m][j] = (f32x4){0.f, 0.f, 0.f, 0.f};

    // ---- pure compute: per kfrag, cvt 2 B-frags then 8 MFMA ----
#pragma unroll
    for (int kf = 0; kf < 8; ++kf) {
        bf16x8 b0 = __builtin_bit_cast(bf16x8, pack8(raw[kf][0][0], raw[kf][0][1]));
        bf16x8 b1 = __builtin_bit_cast(bf16x8, pack8(raw[kf][1][0], raw[kf][1][1]));
#pragma unroll
        for (int m = 0; m < 4; ++m) {
            bf16x8 af = *(const bf16x8*)&Xs[(m * 16 + fr) * LDX + kf * 32 + fk];
            acc[m][0] = __builtin_amdgcn_mfma_f32_16x16x32_bf16(af, b0, acc[m][0], 0, 0, 0);
            acc[m][1] = __builtin_amdgcn_mfma_f32_16x16x32_bf16(af, b1, acc[m][1], 0, 0, 0);
        }
    }

    // ---- epilogue: bf16 partials, row-major [slab][row 0..63][col 0..NNP)
    // wave covers 32 consecutive cols per row -> fully covered 64 B runs
    unsigned short* base = P + (size_t)blockIdx.y * NB * NNP;
#pragma unroll
    for (int j = 0; j < 2; ++j) {
        const int col = n0 + wave * 32 + 16 * j + fr;
#pragma unroll
        for (int m = 0; m < 4; ++m) {
            const int brow = m * 16 + g * 4;
#pragma unroll
            for (int r = 0; r < 4; ++r)
                base[(size_t)(brow + r) * NNP + col] = f2bf(acc[m][j][r]);
        }
    }
}

// thread = 8 consecutive cols of one row; reads 16 B/lane/slab coalesced
__global__ __launch_bounds__(256)
void reduce_splitk(const unsigned short* __restrict__ P, float* __restrict__ out) {
    const int id = blockIdx.x * 256 + threadIdx.x;       // 0 .. 64*NNP/8-1
    const int total = NB * NNP / 8;                      // 35840
    if (id >= total) return;
    const int e0  = id * 8;                              // element in [row][NNP]
    const int row = e0 / NNP;
    const int col = e0 % NNP;

    float s[8] = {0.f, 0.f, 0.f, 0.f, 0.f, 0.f, 0.f, 0.f};
#pragma unroll
    for (int sl = 0; sl < KSPLIT; ++sl) {
        u16x8 v = *(const u16x8*)&P[((size_t)sl * NB + row) * NNP + col];
#pragma unroll
        for (int r = 0; r < 8; ++r)
            s[r] += __uint_as_float((unsigned)v[r] << 16);
    }
#pragma unroll
    for (int r = 0; r < 8; ++r) {
        const int c = col + r;
        if (c < NN) out[(size_t)row * NN + c] = s[r];
    }
}

// ---------------- Fallback (ws too small): R7-style one-pass atomic ----------------
__global__ __launch_bounds__(256, 3)
void gather_gemm_atomic(const float* __restrict__ X,
                        const float* __restrict__ W,
                        const int*   __restrict__ idx,
                        float* __restrict__ out)
{
    __shared__ __align__(16) unsigned short Xs[64 * LDX];
    const int tid  = threadIdx.x;
    const int wave = tid >> 6;
    const int lane = tid & 63;
    const int fr = lane & 15, g = lane >> 4, fk = g * 8;
    const int n0 = blockIdx.x * 64;
    const int kbase = blockIdx.y * KCH;
    const int n = n0 + wave * 16 + fr;
    const int wrow = idx[(n < NN) ? n : (NN - 1)];
    const float* wp = W + (size_t)wrow * D_MODEL + kbase + fk;
    f32x4 wa[8][2];
#pragma unroll
    for (int s = 0; s < 8; ++s) {
        wa[s][0] = *(const f32x4*)(wp + s * 32);
        wa[s][1] = *(const f32x4*)(wp + s * 32 + 4);
    }
    {
        const int row8 = tid >> 5, colf = (tid & 31) * 8;
#pragma unroll
        for (int p = 0; p < 8; ++p) {
            const int row = p * 8 + row8;
            const float* xp = X + (size_t)row * D_MODEL + kbase + colf;
            f32x4 a = *(const f32x4*)(xp + 0);
            f32x4 b = *(const f32x4*)(xp + 4);
            *(u16x8*)&Xs[row * LDX + colf] = pack8(a, b);
        }
    }
    __syncthreads();
    f32x4 acc[4];
#pragma unroll
    for (int m = 0; m < 4; ++m) acc[m] = (f32x4){0.f, 0.f, 0.f, 0.f};
#pragma unroll
    for (int s = 0; s < 8; ++s) {
        bf16x8 wf = __builtin_bit_cast(bf16x8, pack8(wa[s][0], wa[s][1]));
#pragma unroll
        for (int m = 0; m < 4; ++m) {
            bf16x8 af = *(const bf16x8*)&Xs[(m * 16 + fr) * LDX + s * 32 + fk];
            acc[m] = __builtin_amdgcn_mfma_f32_16x16x32_bf16(af, wf, acc[m], 0, 0, 0);
        }
    }
    const int ncol = n0 + wave * 16 + fr;
    if (ncol < NN) {
#pragma unroll
        for (int m = 0; m < 4; ++m) {
            int brow = m * 16 + g * 4;
#pragma unroll
            for (int r = 0; r < 4; ++r)
                atomicAdd(&out[(size_t)(brow + r) * NN + ncol], acc[m][r]);
        }
    }
}

extern "C" void kernel_launch(void* const* d_in, const int* in_sizes, int n_in,
                              void* d_out, int out_size, void* d_ws, size_t ws_size,
                              hipStream_t stream) {
    const float* X   = (const float*)d_in[0];   // [64,1,4096] f32
    const float* W   = (const float*)d_in[1];   // [11008,4096] f32
    const int*   idx = (const int*)d_in[2];     // [4403] i32
    float* out = (float*)d_out;                 // [64,1,4403] f32

    if (ws_size >= WS_NEEDED) {
        unsigned short* P = (unsigned short*)d_ws;
        dim3 grid(NT, KSPLIT, 1);   // 35 x 16 = 560 blocks, 2/CU resident
        gather_gemm<<<grid, 256, 0, stream>>>(X, W, idx, P);
        int total = NB * NNP / 8;   // 35840 threads
        reduce_splitk<<<(total + 255) / 256, 256, 0, stream>>>(P, out);
    } else {
        hipMemsetAsync(d_out, 0, (size_t)out_size * sizeof(float), stream);
        dim3 grid((NN + 63) / 64, KSPLIT, 1);
        gather_gemm_atomic<<<grid, 256, 0, stream>>>(X, W, idx, out);
    }
}